// Round 6
// baseline (818.606 us; speedup 1.0000x reference)
//
#include <hip/hip_runtime.h>
#include <cmath>

// Problem constants (from reference)
#define S_LEN 2048
#define B_SZ 32
#define D_DIM 512
#define H_DIM 512
#define C_NUM 10
#define M_ROWS (S_LEN * B_SZ)   // 65536
#define BH (B_SZ * H_DIM)       // 16384 (= 2^14)
#define N_COLS (3 * H_DIM)      // 1536
#define CH2 32                  // subchunk length for the parallel scan

typedef __bf16 bf16_t;
typedef bf16_t bf16x8 __attribute__((ext_vector_type(8)));
typedef float f32x4 __attribute__((ext_vector_type(4)));
typedef unsigned short ushort_t;

__device__ __forceinline__ unsigned int f2bf(float f) {
  union { float f; unsigned int u; } a;
  a.f = f;
  unsigned int r = a.u + 0x7FFFu + ((a.u >> 16) & 1u);  // RNE
  return r >> 16;
}
__device__ __forceinline__ unsigned int pack2bf(float lo, float hi) {
  return f2bf(lo) | (f2bf(hi) << 16);
}
__device__ __forceinline__ float bfu(ushort_t u) {
  union { unsigned int u; float f; } a; a.u = ((unsigned int)u) << 16; return a.f;
}
__device__ __forceinline__ float sigf(float x) {
  return 1.f / (1.f + __expf(-x));
}
__device__ __forceinline__ float tanh_fast(float c) {
  float e = __expf(2.f * c);
  return 1.f - 2.f / (e + 1.f);
}
__device__ __forceinline__ void load16_lds(const void* g, void* l) {
  __builtin_amdgcn_global_load_lds(
      (const __attribute__((address_space(1))) unsigned int*)g,
      (__attribute__((address_space(3))) unsigned int*)l, 16, 0, 0);
}

// ---------------- gather: E[m][d] = bf16(embed[x[m]][d]) ----------------
__global__ void gather_kernel(const int* __restrict__ x,
                              const float4* __restrict__ embed4,
                              uint4* __restrict__ hb4) {
  int i = blockIdx.x * blockDim.x + threadIdx.x;
  const int total = M_ROWS * (D_DIM / 8);
  int stride = gridDim.x * blockDim.x;
  for (; i < total; i += stride) {
    int m = i >> 6;          // D/8 = 64
    int d2 = (i & 63) * 2;   // float4 index
    const float4* src = &embed4[(size_t)x[m] * 128 + d2];
    float4 a = src[0], bq = src[1];
    hb4[i] = make_uint4(pack2bf(a.x, a.y), pack2bf(a.z, a.w),
                        pack2bf(bq.x, bq.y), pack2bf(bq.z, bq.w));
  }
}

// ---------------- W -> Wt (transpose + bf16): Wt[l][n][k] = W[l][k][n] ----------------
__global__ __launch_bounds__(256) void wt_kernel(const float* __restrict__ W,
                                                 ushort_t* __restrict__ Wt) {
  __shared__ float tile[32][33];
  int bid = blockIdx.x;               // 2 * 48 * 16
  int l = bid / 768;
  int rem = bid - l * 768;
  int nblk = rem >> 4, kblk = rem & 15;
  int n0 = nblk * 32, k0 = kblk * 32;
  int tx = threadIdx.x & 31, ty = threadIdx.x >> 5;  // 32 x 8
  const float* Wl = W + (size_t)l * D_DIM * N_COLS;
#pragma unroll
  for (int r = 0; r < 4; r++)
    tile[ty + r * 8][tx] = Wl[(size_t)(k0 + ty + r * 8) * N_COLS + n0 + tx];
  __syncthreads();
  ushort_t* Wtl = Wt + (size_t)l * N_COLS * D_DIM;
#pragma unroll
  for (int r = 0; r < 4; r++)
    Wtl[(size_t)(n0 + ty + r * 8) * D_DIM + k0 + tx] =
        (ushort_t)f2bf(tile[tx][ty + r * 8]);
}

// ---------------- bf16 MFMA GEMM, raw pre-activation bf16 outputs ----------------
// Tile 128x128, BK=64, 4 waves (2x2), each wave 64x64 = 4x4 frags of 16x16x32.
// MFMA called as mfma(bfr, af) -> D col(lane&15) <-> m, row <-> n, so each lane
// holds 4 consecutive n per fragment -> one 8B packed store per fragment.
__global__ __launch_bounds__(256) void sru_gemm_bf16(
    const ushort_t* __restrict__ A,   // rows x 512 (bf16 bits)
    const ushort_t* __restrict__ Wt,  // 1536 x 512 (bf16 bits)
    ushort_t* __restrict__ xt_out, ushort_t* __restrict__ f_out,
    ushort_t* __restrict__ r_out) {
  __shared__ ushort_t As[8 * 128 * 8];  // [kc][row][8], kc covers k=[8kc,8kc+8)
  __shared__ ushort_t Bs[8 * 128 * 8];
  const int t = threadIdx.x;
  const int wave = t >> 6, lane = t & 63;
  // bijective XCD swizzle (gridDim.x % 8 == 0 for all our grids)
  const int cpx = gridDim.x >> 3;
  const int swz = (blockIdx.x & 7) * cpx + (blockIdx.x >> 3);
  const int nb = swz % 12, mb = swz / 12;
  const int m0 = mb * 128, n0 = nb * 128;
  const int wm = wave & 1, wn = wave >> 1;
  const int lrow = lane >> 4, lcol = lane & 15;

  f32x4 acc[4][4];
#pragma unroll
  for (int i = 0; i < 4; i++)
#pragma unroll
    for (int j = 0; j < 4; j++) acc[i][j] = (f32x4){0.f, 0.f, 0.f, 0.f};

  for (int k0 = 0; k0 < D_DIM; k0 += 64) {
    // wave stages kc = {2w, 2w+1} of both As and Bs (8 loads/wave)
#pragma unroll
    for (int j = 0; j < 2; j++) {
      const int kc = wave * 2 + j;
#pragma unroll
      for (int half = 0; half < 2; half++) {
        load16_lds(A + (size_t)(m0 + half * 64 + lane) * D_DIM + k0 + kc * 8,
                   &As[((kc)*128 + half * 64) * 8]);
        load16_lds(Wt + (size_t)(n0 + half * 64 + lane) * D_DIM + k0 + kc * 8,
                   &Bs[((kc)*128 + half * 64) * 8]);
      }
    }
    __syncthreads();  // drains vmcnt -> LDS tile ready
    bf16x8 af[2][4], bfr[2][4];
#pragma unroll
    for (int ks = 0; ks < 2; ks++) {
#pragma unroll
      for (int mi = 0; mi < 4; mi++)
        af[ks][mi] = *reinterpret_cast<const bf16x8*>(
            &As[((ks * 4 + lrow) * 128 + wm * 64 + mi * 16 + lcol) * 8]);
#pragma unroll
      for (int ni = 0; ni < 4; ni++)
        bfr[ks][ni] = *reinterpret_cast<const bf16x8*>(
            &Bs[((ks * 4 + lrow) * 128 + wn * 64 + ni * 16 + lcol) * 8]);
    }
#pragma unroll
    for (int ks = 0; ks < 2; ks++)
#pragma unroll
      for (int mi = 0; mi < 4; mi++)
#pragma unroll
        for (int ni = 0; ni < 4; ni++)
          acc[mi][ni] = __builtin_amdgcn_mfma_f32_16x16x32_bf16(
              bfr[ks][ni], af[ks][mi], acc[mi][ni], 0, 0, 0);
    __syncthreads();  // reads done before next iter's staging
  }

  // epilogue: swapped mapping -> m = ...+lcol, n = ...+lrow*4+j ; 8B packed stores
  const int region = n0 >> 9;  // 0=xt, 1=f, 2=r
  ushort_t* outp = region == 0 ? xt_out : (region == 1 ? f_out : r_out);
  const int nbase = (n0 & 511) + wn * 64 + lrow * 4;
#pragma unroll
  for (int mi = 0; mi < 4; mi++) {
    const size_t rowoff = (size_t)(m0 + wm * 64 + mi * 16 + lcol) * H_DIM;
#pragma unroll
    for (int ni = 0; ni < 4; ni++) {
      uint2 pk;
      pk.x = pack2bf(acc[mi][ni][0], acc[mi][ni][1]);
      pk.y = pack2bf(acc[mi][ni][2], acc[mi][ni][3]);
      *(uint2*)&outp[rowoff + nbase + ni * 16] = pk;
    }
  }
}

// ---------------- chunk-parallel linear scan (bf16 raw gates, x4 cols/thread) ----------------
// f is a raw pre-activation; sigmoid(+bias) applied on the fly.
__global__ void scan_pass1(const ushort_t* __restrict__ f, const ushort_t* __restrict__ xt,
                           const float* __restrict__ bl,
                           float* __restrict__ Ac, float* __restrict__ Bc) {
  int gid = blockIdx.x * blockDim.x + threadIdx.x;  // nsub * BH/4
  int ch = gid >> 12;
  int col = (gid & 4095) * 4;
  int h = col & 511;
  float4 bfv = *(const float4*)&bl[h];
  size_t base = (size_t)ch * CH2 * BH + col;
  float A0 = 1.f, A1 = 1.f, A2 = 1.f, A3 = 1.f;
  float B0 = 0.f, B1 = 0.f, B2 = 0.f, B3 = 0.f;
#pragma unroll 8
  for (int s = 0; s < CH2; s++) {
    ushort4 fv = *(const ushort4*)&f[base + (size_t)s * BH];
    ushort4 xv = *(const ushort4*)&xt[base + (size_t)s * BH];
    float f0 = sigf(bfu(fv.x) + bfv.x), f1 = sigf(bfu(fv.y) + bfv.y);
    float f2 = sigf(bfu(fv.z) + bfv.z), f3 = sigf(bfu(fv.w) + bfv.w);
    B0 = f0 * B0 + (1.f - f0) * bfu(xv.x);
    B1 = f1 * B1 + (1.f - f1) * bfu(xv.y);
    B2 = f2 * B2 + (1.f - f2) * bfu(xv.z);
    B3 = f3 * B3 + (1.f - f3) * bfu(xv.w);
    A0 *= f0; A1 *= f1; A2 *= f2; A3 *= f3;
  }
  int o = ch * BH + col;
  *(float4*)&Ac[o] = make_float4(A0, A1, A2, A3);
  *(float4*)&Bc[o] = make_float4(B0, B1, B2, B3);
}

__global__ void scan_carry(const float* __restrict__ Ac, const float* __restrict__ Bc,
                           float* __restrict__ carry, float* __restrict__ cstate,
                           int nsub, int first) {
  int rem = blockIdx.x * blockDim.x + threadIdx.x;  // BH
  float c = first ? 0.f : cstate[rem];
  for (int ch = 0; ch < nsub; ch++) {
    int idx = ch * BH + rem;
    carry[idx] = c;
    c = Ac[idx] * c + Bc[idx];
  }
  cstate[rem] = c;
}

// LAST=0: write highway out (bf16). hw and ob are NOT restrict-qualified:
// they MAY alias (in-place over the highway plane) — per-thread load-before-store
// order on the same address is then guaranteed. LAST=1: only pmax.
template <int LAST>
__global__ void scan_pass2(const ushort_t* __restrict__ f, const ushort_t* __restrict__ xt,
                           const ushort_t* __restrict__ r, const ushort_t* hw,
                           ushort_t* ob, const float* __restrict__ bl,
                           const float* __restrict__ carry, float* __restrict__ pmax,
                           int first_outer) {
  int gid = blockIdx.x * blockDim.x + threadIdx.x;  // nsub * BH/4
  int ch = gid >> 12;
  int col = (gid & 4095) * 4;
  int h = col & 511;
  float4 bfv = *(const float4*)&bl[h];
  float4 brv = *(const float4*)&bl[512 + h];
  size_t base = (size_t)ch * CH2 * BH + col;
  float4 cc = *(const float4*)&carry[ch * BH + col];
  float c0 = cc.x, c1 = cc.y, c2 = cc.z, c3 = cc.w;
  float pm0 = -1e30f, pm1 = -1e30f, pm2 = -1e30f, pm3 = -1e30f;
  for (int s = 0; s < CH2; s++) {
    size_t idx = base + (size_t)s * BH;
    ushort4 fv = *(const ushort4*)&f[idx];
    ushort4 xv = *(const ushort4*)&xt[idx];
    ushort4 rv = *(const ushort4*)&r[idx];
    ushort4 hv = *(const ushort4*)&hw[idx];
    float f0 = sigf(bfu(fv.x) + bfv.x), f1 = sigf(bfu(fv.y) + bfv.y);
    float f2 = sigf(bfu(fv.z) + bfv.z), f3 = sigf(bfu(fv.w) + bfv.w);
    float r0 = sigf(bfu(rv.x) + brv.x), r1 = sigf(bfu(rv.y) + brv.y);
    float r2 = sigf(bfu(rv.z) + brv.z), r3 = sigf(bfu(rv.w) + brv.w);
    c0 = f0 * c0 + (1.f - f0) * bfu(xv.x);
    c1 = f1 * c1 + (1.f - f1) * bfu(xv.y);
    c2 = f2 * c2 + (1.f - f2) * bfu(xv.z);
    c3 = f3 * c3 + (1.f - f3) * bfu(xv.w);
    float o0 = r0 * tanh_fast(c0) + (1.f - r0) * bfu(hv.x);
    float o1 = r1 * tanh_fast(c1) + (1.f - r1) * bfu(hv.y);
    float o2 = r2 * tanh_fast(c2) + (1.f - r2) * bfu(hv.z);
    float o3 = r3 * tanh_fast(c3) + (1.f - r3) * bfu(hv.w);
    if (LAST) {
      pm0 = fmaxf(pm0, o0); pm1 = fmaxf(pm1, o1);
      pm2 = fmaxf(pm2, o2); pm3 = fmaxf(pm3, o3);
    } else {
      uint2 pk;
      pk.x = pack2bf(o0, o1);
      pk.y = pack2bf(o2, o3);
      *(uint2*)&ob[idx] = pk;
    }
  }
  if (LAST) {
    int o = ch * BH + col;
    if (first_outer) {
      *(float4*)&pmax[o] = make_float4(pm0, pm1, pm2, pm3);
    } else {
      float4 old = *(const float4*)&pmax[o];
      *(float4*)&pmax[o] = make_float4(fmaxf(old.x, pm0), fmaxf(old.y, pm1),
                                       fmaxf(old.z, pm2), fmaxf(old.w, pm3));
    }
  }
}

// ---------------- pool: max over subchunk slots, double tanh ----------------
__global__ void pool_kernel(const float* __restrict__ pmax, float* __restrict__ pooled,
                            int nsub) {
  int rem = blockIdx.x * blockDim.x + threadIdx.x;  // BH
  float m = -1e30f;
  for (int ch = 0; ch < nsub; ch++) m = fmaxf(m, pmax[ch * BH + rem]);
  pooled[rem] = tanhf(tanhf(m));  // max(tanh(h)) == tanh(max(h)) (monotone)
}

// ---------------- final projection (tiny) ----------------
__global__ void out_gemm(const float* __restrict__ pooled, const float* __restrict__ Wc,
                         const float* __restrict__ bc, float* __restrict__ out) {
  __shared__ float pt[H_DIM];
  int b = blockIdx.x;
  for (int i = threadIdx.x; i < H_DIM; i += blockDim.x) pt[i] = pooled[b * H_DIM + i];
  __syncthreads();
  if (threadIdx.x < C_NUM) {
    int c = threadIdx.x;
    float acc = bc[c];
    for (int hh = 0; hh < H_DIM; hh++) acc = fmaf(pt[hh], Wc[hh * C_NUM + c], acc);
    out[b * C_NUM + c] = acc;
  }
}

extern "C" void kernel_launch(void* const* d_in, const int* in_sizes, int n_in,
                              void* d_out, int out_size, void* d_ws, size_t ws_size,
                              hipStream_t stream) {
  const int* x = (const int*)d_in[0];
  const float* embed = (const float*)d_in[1];
  const float* W = (const float*)d_in[2];
  const float* b = (const float*)d_in[3];
  const float* Wc = (const float*)d_in[4];
  const float* bc = (const float*)d_in[5];
  float* out = (float*)d_out;

  const size_t SZ_HB = (size_t)M_ROWS * H_DIM * 2;   // 64 MiB (bf16 full-S plane)
  const size_t SZ_WT = 2ull * N_COLS * D_DIM * 2;    // 3 MiB
  const size_t SZ_BHf = (size_t)BH * 4;              // 64 KiB

  // mode select: full-S clean (5 planes) > full-S aliased (4 planes) > chunked
  const size_t nsubF = S_LEN / CH2;  // 64
  const size_t fixedF = 2 * SZ_BHf + 4 * nsubF * SZ_BHf + SZ_WT;
  int Sc;
  int clean = 0;
  if (fixedF + 5 * SZ_HB <= ws_size) { Sc = S_LEN; clean = 1; }
  else if (fixedF + 4 * SZ_HB <= ws_size) { Sc = S_LEN; }
  else {
    Sc = 32;
    const int cands[6] = {1024, 512, 256, 128, 64, 32};
    for (int i = 0; i < 6; i++) {
      int c = cands[i];
      size_t nsub = (size_t)c / CH2;
      size_t need = 2 * SZ_BHf + 4 * nsub * SZ_BHf + SZ_WT + 2 * SZ_HB + 3ull * c * BH * 2;
      if (need <= ws_size) { Sc = c; break; }
    }
  }
  const int full = (Sc == S_LEN);
  const int nsub = Sc / CH2;
  const int nouter = S_LEN / Sc;

  char* p = (char*)d_ws;
  float* cstate = (float*)p; p += SZ_BHf;
  float* pooled = (float*)p; p += SZ_BHf;
  float* pmax   = (float*)p; p += (size_t)nsub * SZ_BHf;
  float* Ac     = (float*)p; p += (size_t)nsub * SZ_BHf;
  float* Bc     = (float*)p; p += (size_t)nsub * SZ_BHf;
  float* carry  = (float*)p; p += (size_t)nsub * SZ_BHf;
  ushort_t* Wt  = (ushort_t*)p; p += SZ_WT;
  // planes
  ushort_t* E  = (ushort_t*)p; p += SZ_HB;      // embedding / L0 highway
  ushort_t *X0, *F0, *R0, *O0 = nullptr, *OB = nullptr;
  if (full) {
    X0 = (ushort_t*)p; p += SZ_HB;
    F0 = (ushort_t*)p; p += SZ_HB;
    R0 = (ushort_t*)p; p += SZ_HB;
    O0 = clean ? ((ushort_t*)p) : E;  // clean: 5th plane; else alias highway (UB-free)
  } else {
    OB = (ushort_t*)p; p += SZ_HB;    // chunked: separate full-S output plane
    X0 = (ushort_t*)p; p += (size_t)Sc * BH * 2;
    F0 = (ushort_t*)p; p += (size_t)Sc * BH * 2;
    R0 = (ushort_t*)p;
  }

  gather_kernel<<<2048, 256, 0, stream>>>(x, (const float4*)embed, (uint4*)E);
  wt_kernel<<<1536, 256, 0, stream>>>(W, Wt);

  const int p1_blocks = (nsub * (BH / 4)) / 256;
  const int gemm_blocks = ((Sc * B_SZ) / 128) * (N_COLS / 128);
  for (int l = 0; l < 2; l++) {
    const ushort_t* Wtl = Wt + (size_t)l * N_COLS * D_DIM;
    const float* bl = b + (size_t)l * 2 * H_DIM;
    for (int ci = 0; ci < nouter; ci++) {
      const size_t off = (size_t)ci * Sc * BH;
      const ushort_t* Ain = full ? (l == 0 ? E : O0) : ((l == 0 ? E : OB) + off);
      sru_gemm_bf16<<<gemm_blocks, 256, 0, stream>>>(Ain, Wtl, X0, F0, R0);
      scan_pass1<<<p1_blocks, 256, 0, stream>>>(F0, X0, bl, Ac, Bc);
      scan_carry<<<BH / 256, 256, 0, stream>>>(Ac, Bc, carry, cstate, nsub, ci == 0);
      if (l == 0) {
        const ushort_t* hwp = full ? E : E + off;
        ushort_t* obp = full ? O0 : OB + off;
        scan_pass2<0><<<p1_blocks, 256, 0, stream>>>(F0, X0, R0, hwp, obp, bl, carry,
                                                     pmax, ci == 0);
      } else {
        const ushort_t* hwp = full ? O0 : OB + off;
        scan_pass2<1><<<p1_blocks, 256, 0, stream>>>(F0, X0, R0, hwp, nullptr, bl, carry,
                                                     pmax, ci == 0);
      }
    }
  }

  pool_kernel<<<BH / 256, 256, 0, stream>>>(pmax, pooled, nsub);
  out_gemm<<<B_SZ, 256, 0, stream>>>(pooled, Wc, bc, out);
}

// Round 7
// 772.578 us; speedup vs baseline: 1.0596x; 1.0596x over previous
//
#include <hip/hip_runtime.h>
#include <cmath>

// Problem constants (from reference)
#define S_LEN 2048
#define B_SZ 32
#define D_DIM 512
#define H_DIM 512
#define C_NUM 10
#define M_ROWS (S_LEN * B_SZ)   // 65536
#define BH (B_SZ * H_DIM)       // 16384 (= 2^14)
#define N_COLS (3 * H_DIM)      // 1536
#define CH2 32                  // subchunk length for the parallel scan

typedef __bf16 bf16_t;
typedef bf16_t bf16x8 __attribute__((ext_vector_type(8)));
typedef float f32x4 __attribute__((ext_vector_type(4)));
typedef unsigned short ushort_t;

__device__ __forceinline__ unsigned int f2bf(float f) {
  union { float f; unsigned int u; } a;
  a.f = f;
  unsigned int r = a.u + 0x7FFFu + ((a.u >> 16) & 1u);  // RNE
  return r >> 16;
}
__device__ __forceinline__ unsigned int pack2bf(float lo, float hi) {
  return f2bf(lo) | (f2bf(hi) << 16);
}
__device__ __forceinline__ float bfu(ushort_t u) {
  union { unsigned int u; float f; } a; a.u = ((unsigned int)u) << 16; return a.f;
}
__device__ __forceinline__ float sigf(float x) {
  return 1.f / (1.f + __expf(-x));
}
__device__ __forceinline__ float tanh_fast(float c) {
  float e = __expf(2.f * c);
  return 1.f - 2.f / (e + 1.f);
}
__device__ __forceinline__ void load16_lds(const void* g, void* l) {
  __builtin_amdgcn_global_load_lds(
      (const __attribute__((address_space(1))) unsigned int*)g,
      (__attribute__((address_space(3))) unsigned int*)l, 16, 0, 0);
}

// ---------------- gather: E[m][d] = bf16(embed[x[m]][d]) ----------------
__global__ void gather_kernel(const int* __restrict__ x,
                              const float4* __restrict__ embed4,
                              uint4* __restrict__ hb4) {
  int i = blockIdx.x * blockDim.x + threadIdx.x;
  const int total = M_ROWS * (D_DIM / 8);
  int stride = gridDim.x * blockDim.x;
  for (; i < total; i += stride) {
    int m = i >> 6;          // D/8 = 64
    int d2 = (i & 63) * 2;   // float4 index
    const float4* src = &embed4[(size_t)x[m] * 128 + d2];
    float4 a = src[0], bq = src[1];
    hb4[i] = make_uint4(pack2bf(a.x, a.y), pack2bf(a.z, a.w),
                        pack2bf(bq.x, bq.y), pack2bf(bq.z, bq.w));
  }
}

// ---------------- W -> Wt (transpose + bf16): Wt[l][n][k] = W[l][k][n] ----------------
__global__ __launch_bounds__(256) void wt_kernel(const float* __restrict__ W,
                                                 ushort_t* __restrict__ Wt) {
  __shared__ float tile[32][33];
  int bid = blockIdx.x;               // 2 * 48 * 16
  int l = bid / 768;
  int rem = bid - l * 768;
  int nblk = rem >> 4, kblk = rem & 15;
  int n0 = nblk * 32, k0 = kblk * 32;
  int tx = threadIdx.x & 31, ty = threadIdx.x >> 5;  // 32 x 8
  const float* Wl = W + (size_t)l * D_DIM * N_COLS;
#pragma unroll
  for (int r = 0; r < 4; r++)
    tile[ty + r * 8][tx] = Wl[(size_t)(k0 + ty + r * 8) * N_COLS + n0 + tx];
  __syncthreads();
  ushort_t* Wtl = Wt + (size_t)l * N_COLS * D_DIM;
#pragma unroll
  for (int r = 0; r < 4; r++)
    Wtl[(size_t)(n0 + ty + r * 8) * D_DIM + k0 + tx] =
        (ushort_t)f2bf(tile[tx][ty + r * 8]);
}

// ---------------- bf16 MFMA GEMM, raw pre-activation bf16 outputs ----------------
// m97-point: tile 128x128, BK=32 (16 KB LDS total), 4 waves (2x2),
// each wave 64x64 = 4x4 frags of 16x16x32, 16 K-steps.
// mfma(bfr, af) -> D col(lane&15) <-> m, row <-> n: 8B packed stores.
__global__ __launch_bounds__(256, 3) void sru_gemm_bf16(
    const ushort_t* __restrict__ A,   // rows x 512 (bf16 bits)
    const ushort_t* __restrict__ Wt,  // 1536 x 512 (bf16 bits)
    ushort_t* __restrict__ xt_out, ushort_t* __restrict__ f_out,
    ushort_t* __restrict__ r_out) {
  __shared__ ushort_t As[4 * 128 * 8];  // [kc][row][8], kc covers k=[8kc,8kc+8)
  __shared__ ushort_t Bs[4 * 128 * 8];
  const int t = threadIdx.x;
  const int wave = t >> 6, lane = t & 63;
  // bijective XCD swizzle (gridDim.x % 8 == 0 for all our grids)
  const int cpx = gridDim.x >> 3;
  const int swz = (blockIdx.x & 7) * cpx + (blockIdx.x >> 3);
  const int nb = swz % 12, mb = swz / 12;
  const int m0 = mb * 128, n0 = nb * 128;
  const int wm = wave & 1, wn = wave >> 1;
  const int lrow = lane >> 4, lcol = lane & 15;

  f32x4 acc[4][4];
#pragma unroll
  for (int i = 0; i < 4; i++)
#pragma unroll
    for (int j = 0; j < 4; j++) acc[i][j] = (f32x4){0.f, 0.f, 0.f, 0.f};

  // per K-step: wave stages subtile kc=wave of As and Bs (4 x 1KB loads/wave)
  const ushort_t* gA0 = A + (size_t)(m0 + lane) * D_DIM + wave * 8;
  const ushort_t* gA1 = A + (size_t)(m0 + 64 + lane) * D_DIM + wave * 8;
  const ushort_t* gB0 = Wt + (size_t)(n0 + lane) * D_DIM + wave * 8;
  const ushort_t* gB1 = Wt + (size_t)(n0 + 64 + lane) * D_DIM + wave * 8;
  ushort_t* lA0 = &As[(wave * 128 + 0) * 8];
  ushort_t* lA1 = &As[(wave * 128 + 64) * 8];
  ushort_t* lB0 = &Bs[(wave * 128 + 0) * 8];
  ushort_t* lB1 = &Bs[(wave * 128 + 64) * 8];

  for (int k0 = 0; k0 < D_DIM; k0 += 32) {
    load16_lds(gA0 + k0, lA0);
    load16_lds(gA1 + k0, lA1);
    load16_lds(gB0 + k0, lB0);
    load16_lds(gB1 + k0, lB1);
    __syncthreads();  // drains vmcnt -> LDS tile ready
    bf16x8 af[4], bfr[4];
#pragma unroll
    for (int mi = 0; mi < 4; mi++)
      af[mi] = *reinterpret_cast<const bf16x8*>(
          &As[(lrow * 128 + wm * 64 + mi * 16 + lcol) * 8]);
#pragma unroll
    for (int ni = 0; ni < 4; ni++)
      bfr[ni] = *reinterpret_cast<const bf16x8*>(
          &Bs[(lrow * 128 + wn * 64 + ni * 16 + lcol) * 8]);
#pragma unroll
    for (int mi = 0; mi < 4; mi++)
#pragma unroll
      for (int ni = 0; ni < 4; ni++)
        acc[mi][ni] = __builtin_amdgcn_mfma_f32_16x16x32_bf16(
            bfr[ni], af[mi], acc[mi][ni], 0, 0, 0);
    __syncthreads();  // reads done before next iter's staging
  }

  // epilogue: swapped mapping -> m = ...+lcol, n = ...+lrow*4+j ; 8B packed stores
  const int region = n0 >> 9;  // 0=xt, 1=f, 2=r
  ushort_t* outp = region == 0 ? xt_out : (region == 1 ? f_out : r_out);
  const int nbase = (n0 & 511) + wn * 64 + lrow * 4;
#pragma unroll
  for (int mi = 0; mi < 4; mi++) {
    const size_t rowoff = (size_t)(m0 + wm * 64 + mi * 16 + lcol) * H_DIM;
#pragma unroll
    for (int ni = 0; ni < 4; ni++) {
      uint2 pk;
      pk.x = pack2bf(acc[mi][ni][0], acc[mi][ni][1]);
      pk.y = pack2bf(acc[mi][ni][2], acc[mi][ni][3]);
      *(uint2*)&outp[rowoff + nbase + ni * 16] = pk;
    }
  }
}

// ---------------- chunk-parallel linear scan (bf16 raw gates, x4 cols/thread) ----------------
// f is a raw pre-activation; sigmoid(+bias) applied on the fly.
__global__ void scan_pass1(const ushort_t* __restrict__ f, const ushort_t* __restrict__ xt,
                           const float* __restrict__ bl,
                           float* __restrict__ Ac, float* __restrict__ Bc) {
  int gid = blockIdx.x * blockDim.x + threadIdx.x;  // nsub * BH/4
  int ch = gid >> 12;
  int col = (gid & 4095) * 4;
  int h = col & 511;
  float4 bfv = *(const float4*)&bl[h];
  size_t base = (size_t)ch * CH2 * BH + col;
  float A0 = 1.f, A1 = 1.f, A2 = 1.f, A3 = 1.f;
  float B0 = 0.f, B1 = 0.f, B2 = 0.f, B3 = 0.f;
#pragma unroll 8
  for (int s = 0; s < CH2; s++) {
    ushort4 fv = *(const ushort4*)&f[base + (size_t)s * BH];
    ushort4 xv = *(const ushort4*)&xt[base + (size_t)s * BH];
    float f0 = sigf(bfu(fv.x) + bfv.x), f1 = sigf(bfu(fv.y) + bfv.y);
    float f2 = sigf(bfu(fv.z) + bfv.z), f3 = sigf(bfu(fv.w) + bfv.w);
    B0 = f0 * B0 + (1.f - f0) * bfu(xv.x);
    B1 = f1 * B1 + (1.f - f1) * bfu(xv.y);
    B2 = f2 * B2 + (1.f - f2) * bfu(xv.z);
    B3 = f3 * B3 + (1.f - f3) * bfu(xv.w);
    A0 *= f0; A1 *= f1; A2 *= f2; A3 *= f3;
  }
  int o = ch * BH + col;
  *(float4*)&Ac[o] = make_float4(A0, A1, A2, A3);
  *(float4*)&Bc[o] = make_float4(B0, B1, B2, B3);
}

__global__ void scan_carry(const float* __restrict__ Ac, const float* __restrict__ Bc,
                           float* __restrict__ carry, float* __restrict__ cstate,
                           int nsub, int first) {
  int rem = blockIdx.x * blockDim.x + threadIdx.x;  // BH
  float c = first ? 0.f : cstate[rem];
  for (int ch = 0; ch < nsub; ch++) {
    int idx = ch * BH + rem;
    carry[idx] = c;
    c = Ac[idx] * c + Bc[idx];
  }
  cstate[rem] = c;
}

// LAST=0: write highway out (bf16). hw and ob are NOT restrict-qualified:
// they MAY alias (in-place over the highway plane) — per-thread load-before-store
// order on the same address is then guaranteed. LAST=1: only pmax.
template <int LAST>
__global__ void scan_pass2(const ushort_t* __restrict__ f, const ushort_t* __restrict__ xt,
                           const ushort_t* __restrict__ r, const ushort_t* hw,
                           ushort_t* ob, const float* __restrict__ bl,
                           const float* __restrict__ carry, float* __restrict__ pmax,
                           int first_outer) {
  int gid = blockIdx.x * blockDim.x + threadIdx.x;  // nsub * BH/4
  int ch = gid >> 12;
  int col = (gid & 4095) * 4;
  int h = col & 511;
  float4 bfv = *(const float4*)&bl[h];
  float4 brv = *(const float4*)&bl[512 + h];
  size_t base = (size_t)ch * CH2 * BH + col;
  float4 cc = *(const float4*)&carry[ch * BH + col];
  float c0 = cc.x, c1 = cc.y, c2 = cc.z, c3 = cc.w;
  float pm0 = -1e30f, pm1 = -1e30f, pm2 = -1e30f, pm3 = -1e30f;
  for (int s = 0; s < CH2; s++) {
    size_t idx = base + (size_t)s * BH;
    ushort4 fv = *(const ushort4*)&f[idx];
    ushort4 xv = *(const ushort4*)&xt[idx];
    ushort4 rv = *(const ushort4*)&r[idx];
    ushort4 hv = *(const ushort4*)&hw[idx];
    float f0 = sigf(bfu(fv.x) + bfv.x), f1 = sigf(bfu(fv.y) + bfv.y);
    float f2 = sigf(bfu(fv.z) + bfv.z), f3 = sigf(bfu(fv.w) + bfv.w);
    float r0 = sigf(bfu(rv.x) + brv.x), r1 = sigf(bfu(rv.y) + brv.y);
    float r2 = sigf(bfu(rv.z) + brv.z), r3 = sigf(bfu(rv.w) + brv.w);
    c0 = f0 * c0 + (1.f - f0) * bfu(xv.x);
    c1 = f1 * c1 + (1.f - f1) * bfu(xv.y);
    c2 = f2 * c2 + (1.f - f2) * bfu(xv.z);
    c3 = f3 * c3 + (1.f - f3) * bfu(xv.w);
    float o0 = r0 * tanh_fast(c0) + (1.f - r0) * bfu(hv.x);
    float o1 = r1 * tanh_fast(c1) + (1.f - r1) * bfu(hv.y);
    float o2 = r2 * tanh_fast(c2) + (1.f - r2) * bfu(hv.z);
    float o3 = r3 * tanh_fast(c3) + (1.f - r3) * bfu(hv.w);
    if (LAST) {
      pm0 = fmaxf(pm0, o0); pm1 = fmaxf(pm1, o1);
      pm2 = fmaxf(pm2, o2); pm3 = fmaxf(pm3, o3);
    } else {
      uint2 pk;
      pk.x = pack2bf(o0, o1);
      pk.y = pack2bf(o2, o3);
      *(uint2*)&ob[idx] = pk;
    }
  }
  if (LAST) {
    int o = ch * BH + col;
    if (first_outer) {
      *(float4*)&pmax[o] = make_float4(pm0, pm1, pm2, pm3);
    } else {
      float4 old = *(const float4*)&pmax[o];
      *(float4*)&pmax[o] = make_float4(fmaxf(old.x, pm0), fmaxf(old.y, pm1),
                                       fmaxf(old.z, pm2), fmaxf(old.w, pm3));
    }
  }
}

// ---------------- pool: max over subchunk slots, double tanh ----------------
__global__ void pool_kernel(const float* __restrict__ pmax, float* __restrict__ pooled,
                            int nsub) {
  int rem = blockIdx.x * blockDim.x + threadIdx.x;  // BH
  float m = -1e30f;
  for (int ch = 0; ch < nsub; ch++) m = fmaxf(m, pmax[ch * BH + rem]);
  pooled[rem] = tanhf(tanhf(m));  // max(tanh(h)) == tanh(max(h)) (monotone)
}

// ---------------- final projection (tiny) ----------------
__global__ void out_gemm(const float* __restrict__ pooled, const float* __restrict__ Wc,
                         const float* __restrict__ bc, float* __restrict__ out) {
  __shared__ float pt[H_DIM];
  int b = blockIdx.x;
  for (int i = threadIdx.x; i < H_DIM; i += blockDim.x) pt[i] = pooled[b * H_DIM + i];
  __syncthreads();
  if (threadIdx.x < C_NUM) {
    int c = threadIdx.x;
    float acc = bc[c];
    for (int hh = 0; hh < H_DIM; hh++) acc = fmaf(pt[hh], Wc[hh * C_NUM + c], acc);
    out[b * C_NUM + c] = acc;
  }
}

extern "C" void kernel_launch(void* const* d_in, const int* in_sizes, int n_in,
                              void* d_out, int out_size, void* d_ws, size_t ws_size,
                              hipStream_t stream) {
  const int* x = (const int*)d_in[0];
  const float* embed = (const float*)d_in[1];
  const float* W = (const float*)d_in[2];
  const float* b = (const float*)d_in[3];
  const float* Wc = (const float*)d_in[4];
  const float* bc = (const float*)d_in[5];
  float* out = (float*)d_out;

  const size_t SZ_HB = (size_t)M_ROWS * H_DIM * 2;   // 64 MiB (bf16 full-S plane)
  const size_t SZ_WT = 2ull * N_COLS * D_DIM * 2;    // 3 MiB
  const size_t SZ_BHf = (size_t)BH * 4;              // 64 KiB

  // mode select: full-S clean (5 planes) > full-S aliased (4 planes) > chunked
  const size_t nsubF = S_LEN / CH2;  // 64
  const size_t fixedF = 2 * SZ_BHf + 4 * nsubF * SZ_BHf + SZ_WT;
  int Sc;
  int clean = 0;
  if (fixedF + 5 * SZ_HB <= ws_size) { Sc = S_LEN; clean = 1; }
  else if (fixedF + 4 * SZ_HB <= ws_size) { Sc = S_LEN; }
  else {
    Sc = 32;
    const int cands[6] = {1024, 512, 256, 128, 64, 32};
    for (int i = 0; i < 6; i++) {
      int c = cands[i];
      size_t nsub = (size_t)c / CH2;
      size_t need = 2 * SZ_BHf + 4 * nsub * SZ_BHf + SZ_WT + 2 * SZ_HB + 3ull * c * BH * 2;
      if (need <= ws_size) { Sc = c; break; }
    }
  }
  const int full = (Sc == S_LEN);
  const int nsub = Sc / CH2;
  const int nouter = S_LEN / Sc;

  char* p = (char*)d_ws;
  float* cstate = (float*)p; p += SZ_BHf;
  float* pooled = (float*)p; p += SZ_BHf;
  float* pmax   = (float*)p; p += (size_t)nsub * SZ_BHf;
  float* Ac     = (float*)p; p += (size_t)nsub * SZ_BHf;
  float* Bc     = (float*)p; p += (size_t)nsub * SZ_BHf;
  float* carry  = (float*)p; p += (size_t)nsub * SZ_BHf;
  ushort_t* Wt  = (ushort_t*)p; p += SZ_WT;
  // planes
  ushort_t* E  = (ushort_t*)p; p += SZ_HB;      // embedding / L0 highway
  ushort_t *X0, *F0, *R0, *O0 = nullptr, *OB = nullptr;
  if (full) {
    X0 = (ushort_t*)p; p += SZ_HB;
    F0 = (ushort_t*)p; p += SZ_HB;
    R0 = (ushort_t*)p; p += SZ_HB;
    O0 = clean ? ((ushort_t*)p) : E;  // clean: 5th plane; else alias highway (UB-free)
  } else {
    OB = (ushort_t*)p; p += SZ_HB;    // chunked: separate full-S output plane
    X0 = (ushort_t*)p; p += (size_t)Sc * BH * 2;
    F0 = (ushort_t*)p; p += (size_t)Sc * BH * 2;
    R0 = (ushort_t*)p;
  }

  gather_kernel<<<2048, 256, 0, stream>>>(x, (const float4*)embed, (uint4*)E);
  wt_kernel<<<1536, 256, 0, stream>>>(W, Wt);

  const int p1_blocks = (nsub * (BH / 4)) / 256;
  const int gemm_blocks = ((Sc * B_SZ) / 128) * (N_COLS / 128);
  for (int l = 0; l < 2; l++) {
    const ushort_t* Wtl = Wt + (size_t)l * N_COLS * D_DIM;
    const float* bl = b + (size_t)l * 2 * H_DIM;
    for (int ci = 0; ci < nouter; ci++) {
      const size_t off = (size_t)ci * Sc * BH;
      const ushort_t* Ain = full ? (l == 0 ? E : O0) : ((l == 0 ? E : OB) + off);
      sru_gemm_bf16<<<gemm_blocks, 256, 0, stream>>>(Ain, Wtl, X0, F0, R0);
      scan_pass1<<<p1_blocks, 256, 0, stream>>>(F0, X0, bl, Ac, Bc);
      scan_carry<<<BH / 256, 256, 0, stream>>>(Ac, Bc, carry, cstate, nsub, ci == 0);
      if (l == 0) {
        const ushort_t* hwp = full ? E : E + off;
        ushort_t* obp = full ? O0 : OB + off;
        scan_pass2<0><<<p1_blocks, 256, 0, stream>>>(F0, X0, R0, hwp, obp, bl, carry,
                                                     pmax, ci == 0);
      } else {
        const ushort_t* hwp = full ? O0 : OB + off;
        scan_pass2<1><<<p1_blocks, 256, 0, stream>>>(F0, X0, R0, hwp, nullptr, bl, carry,
                                                     pmax, ci == 0);
      }
    }
  }

  pool_kernel<<<BH / 256, 256, 0, stream>>>(pmax, pooled, nsub);
  out_gemm<<<B_SZ, 256, 0, stream>>>(pooled, Wc, bc, out);
}

// Round 8
// 766.225 us; speedup vs baseline: 1.0684x; 1.0083x over previous
//
#include <hip/hip_runtime.h>
#include <cmath>

// Problem constants (from reference)
#define S_LEN 2048
#define B_SZ 32
#define D_DIM 512
#define H_DIM 512
#define C_NUM 10
#define M_ROWS (S_LEN * B_SZ)   // 65536
#define BH (B_SZ * H_DIM)       // 16384 (= 2^14)
#define N_COLS (3 * H_DIM)      // 1536
#define CH2 32                  // subchunk length for the parallel scan

typedef __bf16 bf16_t;
typedef bf16_t bf16x8 __attribute__((ext_vector_type(8)));
typedef float f32x4 __attribute__((ext_vector_type(4)));
typedef unsigned short ushort_t;

__device__ __forceinline__ unsigned int f2bf(float f) {
  union { float f; unsigned int u; } a;
  a.f = f;
  unsigned int r = a.u + 0x7FFFu + ((a.u >> 16) & 1u);  // RNE
  return r >> 16;
}
__device__ __forceinline__ unsigned int pack2bf(float lo, float hi) {
  return f2bf(lo) | (f2bf(hi) << 16);
}
__device__ __forceinline__ float bfu(ushort_t u) {
  union { unsigned int u; float f; } a; a.u = ((unsigned int)u) << 16; return a.f;
}
__device__ __forceinline__ float sigf(float x) {
  return 1.f / (1.f + __expf(-x));
}
__device__ __forceinline__ float tanh_fast(float c) {
  float e = __expf(2.f * c);
  return 1.f - 2.f / (e + 1.f);
}
__device__ __forceinline__ void load16_lds(const void* g, void* l) {
  __builtin_amdgcn_global_load_lds(
      (const __attribute__((address_space(1))) unsigned int*)g,
      (__attribute__((address_space(3))) unsigned int*)l, 16, 0, 0);
}

// ---------------- gather: E[m][d] = bf16(embed[x[m]][d]) ----------------
__global__ void gather_kernel(const int* __restrict__ x,
                              const float4* __restrict__ embed4,
                              uint4* __restrict__ hb4) {
  int i = blockIdx.x * blockDim.x + threadIdx.x;
  const int total = M_ROWS * (D_DIM / 8);
  int stride = gridDim.x * blockDim.x;
  for (; i < total; i += stride) {
    int m = i >> 6;          // D/8 = 64
    int d2 = (i & 63) * 2;   // float4 index
    const float4* src = &embed4[(size_t)x[m] * 128 + d2];
    float4 a = src[0], bq = src[1];
    hb4[i] = make_uint4(pack2bf(a.x, a.y), pack2bf(a.z, a.w),
                        pack2bf(bq.x, bq.y), pack2bf(bq.z, bq.w));
  }
}

// ---------------- W -> Wt (transpose + bf16): Wt[l][n][k] = W[l][k][n] ----------------
__global__ __launch_bounds__(256) void wt_kernel(const float* __restrict__ W,
                                                 ushort_t* __restrict__ Wt) {
  __shared__ float tile[32][33];
  int bid = blockIdx.x;               // 2 * 48 * 16
  int l = bid / 768;
  int rem = bid - l * 768;
  int nblk = rem >> 4, kblk = rem & 15;
  int n0 = nblk * 32, k0 = kblk * 32;
  int tx = threadIdx.x & 31, ty = threadIdx.x >> 5;  // 32 x 8
  const float* Wl = W + (size_t)l * D_DIM * N_COLS;
#pragma unroll
  for (int r = 0; r < 4; r++)
    tile[ty + r * 8][tx] = Wl[(size_t)(k0 + ty + r * 8) * N_COLS + n0 + tx];
  __syncthreads();
  ushort_t* Wtl = Wt + (size_t)l * N_COLS * D_DIM;
#pragma unroll
  for (int r = 0; r < 4; r++)
    Wtl[(size_t)(n0 + ty + r * 8) * D_DIM + k0 + tx] =
        (ushort_t)f2bf(tile[tx][ty + r * 8]);
}

// ---------------- bf16 MFMA GEMM, raw pre-activation bf16 outputs ----------------
// Tile 128x128, BK=32, DOUBLE-BUFFERED 2-phase K-loop (T3-minimum):
// stage tile k+1, compute tile k, one barrier/step (implicit vmcnt drain
// waits for loads that had the whole compute phase in flight).
// mfma(bfr, af) -> D col(lane&15) <-> m, row <-> n: 8B packed stores.
__global__ __launch_bounds__(256, 3) void sru_gemm_bf16(
    const ushort_t* __restrict__ A,   // rows x 512 (bf16 bits)
    const ushort_t* __restrict__ Wt,  // 1536 x 512 (bf16 bits)
    ushort_t* __restrict__ xt_out, ushort_t* __restrict__ f_out,
    ushort_t* __restrict__ r_out) {
  __shared__ ushort_t As[2][4 * 128 * 8];  // [buf][kc][row][8], 8 KB each
  __shared__ ushort_t Bs[2][4 * 128 * 8];
  const int t = threadIdx.x;
  const int wave = t >> 6, lane = t & 63;
  // bijective XCD swizzle (gridDim.x % 8 == 0 for all our grids)
  const int cpx = gridDim.x >> 3;
  const int swz = (blockIdx.x & 7) * cpx + (blockIdx.x >> 3);
  const int nb = swz % 12, mb = swz / 12;
  const int m0 = mb * 128, n0 = nb * 128;
  const int wm = wave & 1, wn = wave >> 1;
  const int lrow = lane >> 4, lcol = lane & 15;

  f32x4 acc[4][4];
#pragma unroll
  for (int i = 0; i < 4; i++)
#pragma unroll
    for (int j = 0; j < 4; j++) acc[i][j] = (f32x4){0.f, 0.f, 0.f, 0.f};

  // per K-step: wave stages subtile kc=wave of As and Bs (4 x 1KB loads/wave)
  const ushort_t* gA0 = A + (size_t)(m0 + lane) * D_DIM + wave * 8;
  const ushort_t* gA1 = A + (size_t)(m0 + 64 + lane) * D_DIM + wave * 8;
  const ushort_t* gB0 = Wt + (size_t)(n0 + lane) * D_DIM + wave * 8;
  const ushort_t* gB1 = Wt + (size_t)(n0 + 64 + lane) * D_DIM + wave * 8;
  const int la0 = (wave * 128 + 0) * 8;
  const int la1 = (wave * 128 + 64) * 8;

#define STAGE(buf, k0)                      \
  do {                                      \
    load16_lds(gA0 + (k0), &As[buf][la0]);  \
    load16_lds(gA1 + (k0), &As[buf][la1]);  \
    load16_lds(gB0 + (k0), &Bs[buf][la0]);  \
    load16_lds(gB1 + (k0), &Bs[buf][la1]);  \
  } while (0)

  STAGE(0, 0);
  __syncthreads();  // drain prologue loads
  int cur = 0;
  for (int step = 0; step < 16; ++step) {
    if (step + 1 < 16) STAGE(cur ^ 1, (step + 1) * 32);  // prefetch next tile
    bf16x8 af[4], bfr[4];
#pragma unroll
    for (int mi = 0; mi < 4; mi++)
      af[mi] = *reinterpret_cast<const bf16x8*>(
          &As[cur][(lrow * 128 + wm * 64 + mi * 16 + lcol) * 8]);
#pragma unroll
    for (int ni = 0; ni < 4; ni++)
      bfr[ni] = *reinterpret_cast<const bf16x8*>(
          &Bs[cur][(lrow * 128 + wn * 64 + ni * 16 + lcol) * 8]);
#pragma unroll
    for (int mi = 0; mi < 4; mi++)
#pragma unroll
      for (int ni = 0; ni < 4; ni++)
        acc[mi][ni] = __builtin_amdgcn_mfma_f32_16x16x32_bf16(
            bfr[ni], af[mi], acc[mi][ni], 0, 0, 0);
    __syncthreads();  // drains vmcnt (prefetch landed) + all reads of buf[cur] done
    cur ^= 1;
  }
#undef STAGE

  // epilogue: swapped mapping -> m = ...+lcol, n = ...+lrow*4+j ; 8B packed stores
  const int region = n0 >> 9;  // 0=xt, 1=f, 2=r
  ushort_t* outp = region == 0 ? xt_out : (region == 1 ? f_out : r_out);
  const int nbase = (n0 & 511) + wn * 64 + lrow * 4;
#pragma unroll
  for (int mi = 0; mi < 4; mi++) {
    const size_t rowoff = (size_t)(m0 + wm * 64 + mi * 16 + lcol) * H_DIM;
#pragma unroll
    for (int ni = 0; ni < 4; ni++) {
      uint2 pk;
      pk.x = pack2bf(acc[mi][ni][0], acc[mi][ni][1]);
      pk.y = pack2bf(acc[mi][ni][2], acc[mi][ni][3]);
      *(uint2*)&outp[rowoff + nbase + ni * 16] = pk;
    }
  }
}

// ---------------- chunk-parallel linear scan (bf16 raw gates, x4 cols/thread) ----------------
// f is a raw pre-activation; sigmoid(+bias) applied on the fly.
__global__ void scan_pass1(const ushort_t* __restrict__ f, const ushort_t* __restrict__ xt,
                           const float* __restrict__ bl,
                           float* __restrict__ Ac, float* __restrict__ Bc) {
  int gid = blockIdx.x * blockDim.x + threadIdx.x;  // nsub * BH/4
  int ch = gid >> 12;
  int col = (gid & 4095) * 4;
  int h = col & 511;
  float4 bfv = *(const float4*)&bl[h];
  size_t base = (size_t)ch * CH2 * BH + col;
  float A0 = 1.f, A1 = 1.f, A2 = 1.f, A3 = 1.f;
  float B0 = 0.f, B1 = 0.f, B2 = 0.f, B3 = 0.f;
#pragma unroll 8
  for (int s = 0; s < CH2; s++) {
    ushort4 fv = *(const ushort4*)&f[base + (size_t)s * BH];
    ushort4 xv = *(const ushort4*)&xt[base + (size_t)s * BH];
    float f0 = sigf(bfu(fv.x) + bfv.x), f1 = sigf(bfu(fv.y) + bfv.y);
    float f2 = sigf(bfu(fv.z) + bfv.z), f3 = sigf(bfu(fv.w) + bfv.w);
    B0 = f0 * B0 + (1.f - f0) * bfu(xv.x);
    B1 = f1 * B1 + (1.f - f1) * bfu(xv.y);
    B2 = f2 * B2 + (1.f - f2) * bfu(xv.z);
    B3 = f3 * B3 + (1.f - f3) * bfu(xv.w);
    A0 *= f0; A1 *= f1; A2 *= f2; A3 *= f3;
  }
  int o = ch * BH + col;
  *(float4*)&Ac[o] = make_float4(A0, A1, A2, A3);
  *(float4*)&Bc[o] = make_float4(B0, B1, B2, B3);
}

__global__ void scan_carry(const float* __restrict__ Ac, const float* __restrict__ Bc,
                           float* __restrict__ carry, float* __restrict__ cstate,
                           int nsub, int first) {
  int rem = blockIdx.x * blockDim.x + threadIdx.x;  // BH
  float c = first ? 0.f : cstate[rem];
  for (int ch = 0; ch < nsub; ch++) {
    int idx = ch * BH + rem;
    carry[idx] = c;
    c = Ac[idx] * c + Bc[idx];
  }
  cstate[rem] = c;
}

// LAST=0: write highway out (bf16). hw and ob are NOT restrict-qualified:
// they MAY alias (in-place over the highway plane) — per-thread load-before-store
// order on the same address is then guaranteed. LAST=1: only pmax.
template <int LAST>
__global__ void scan_pass2(const ushort_t* __restrict__ f, const ushort_t* __restrict__ xt,
                           const ushort_t* __restrict__ r, const ushort_t* hw,
                           ushort_t* ob, const float* __restrict__ bl,
                           const float* __restrict__ carry, float* __restrict__ pmax,
                           int first_outer) {
  int gid = blockIdx.x * blockDim.x + threadIdx.x;  // nsub * BH/4
  int ch = gid >> 12;
  int col = (gid & 4095) * 4;
  int h = col & 511;
  float4 bfv = *(const float4*)&bl[h];
  float4 brv = *(const float4*)&bl[512 + h];
  size_t base = (size_t)ch * CH2 * BH + col;
  float4 cc = *(const float4*)&carry[ch * BH + col];
  float c0 = cc.x, c1 = cc.y, c2 = cc.z, c3 = cc.w;
  float pm0 = -1e30f, pm1 = -1e30f, pm2 = -1e30f, pm3 = -1e30f;
  for (int s = 0; s < CH2; s++) {
    size_t idx = base + (size_t)s * BH;
    ushort4 fv = *(const ushort4*)&f[idx];
    ushort4 xv = *(const ushort4*)&xt[idx];
    ushort4 rv = *(const ushort4*)&r[idx];
    ushort4 hv = *(const ushort4*)&hw[idx];
    float f0 = sigf(bfu(fv.x) + bfv.x), f1 = sigf(bfu(fv.y) + bfv.y);
    float f2 = sigf(bfu(fv.z) + bfv.z), f3 = sigf(bfu(fv.w) + bfv.w);
    float r0 = sigf(bfu(rv.x) + brv.x), r1 = sigf(bfu(rv.y) + brv.y);
    float r2 = sigf(bfu(rv.z) + brv.z), r3 = sigf(bfu(rv.w) + brv.w);
    c0 = f0 * c0 + (1.f - f0) * bfu(xv.x);
    c1 = f1 * c1 + (1.f - f1) * bfu(xv.y);
    c2 = f2 * c2 + (1.f - f2) * bfu(xv.z);
    c3 = f3 * c3 + (1.f - f3) * bfu(xv.w);
    float o0 = r0 * tanh_fast(c0) + (1.f - r0) * bfu(hv.x);
    float o1 = r1 * tanh_fast(c1) + (1.f - r1) * bfu(hv.y);
    float o2 = r2 * tanh_fast(c2) + (1.f - r2) * bfu(hv.z);
    float o3 = r3 * tanh_fast(c3) + (1.f - r3) * bfu(hv.w);
    if (LAST) {
      pm0 = fmaxf(pm0, o0); pm1 = fmaxf(pm1, o1);
      pm2 = fmaxf(pm2, o2); pm3 = fmaxf(pm3, o3);
    } else {
      uint2 pk;
      pk.x = pack2bf(o0, o1);
      pk.y = pack2bf(o2, o3);
      *(uint2*)&ob[idx] = pk;
    }
  }
  if (LAST) {
    int o = ch * BH + col;
    if (first_outer) {
      *(float4*)&pmax[o] = make_float4(pm0, pm1, pm2, pm3);
    } else {
      float4 old = *(const float4*)&pmax[o];
      *(float4*)&pmax[o] = make_float4(fmaxf(old.x, pm0), fmaxf(old.y, pm1),
                                       fmaxf(old.z, pm2), fmaxf(old.w, pm3));
    }
  }
}

// ---------------- pool: max over subchunk slots, double tanh ----------------
__global__ void pool_kernel(const float* __restrict__ pmax, float* __restrict__ pooled,
                            int nsub) {
  int rem = blockIdx.x * blockDim.x + threadIdx.x;  // BH
  float m = -1e30f;
  for (int ch = 0; ch < nsub; ch++) m = fmaxf(m, pmax[ch * BH + rem]);
  pooled[rem] = tanhf(tanhf(m));  // max(tanh(h)) == tanh(max(h)) (monotone)
}

// ---------------- final projection (tiny) ----------------
__global__ void out_gemm(const float* __restrict__ pooled, const float* __restrict__ Wc,
                         const float* __restrict__ bc, float* __restrict__ out) {
  __shared__ float pt[H_DIM];
  int b = blockIdx.x;
  for (int i = threadIdx.x; i < H_DIM; i += blockDim.x) pt[i] = pooled[b * H_DIM + i];
  __syncthreads();
  if (threadIdx.x < C_NUM) {
    int c = threadIdx.x;
    float acc = bc[c];
    for (int hh = 0; hh < H_DIM; hh++) acc = fmaf(pt[hh], Wc[hh * C_NUM + c], acc);
    out[b * C_NUM + c] = acc;
  }
}

extern "C" void kernel_launch(void* const* d_in, const int* in_sizes, int n_in,
                              void* d_out, int out_size, void* d_ws, size_t ws_size,
                              hipStream_t stream) {
  const int* x = (const int*)d_in[0];
  const float* embed = (const float*)d_in[1];
  const float* W = (const float*)d_in[2];
  const float* b = (const float*)d_in[3];
  const float* Wc = (const float*)d_in[4];
  const float* bc = (const float*)d_in[5];
  float* out = (float*)d_out;

  const size_t SZ_HB = (size_t)M_ROWS * H_DIM * 2;   // 64 MiB (bf16 full-S plane)
  const size_t SZ_WT = 2ull * N_COLS * D_DIM * 2;    // 3 MiB
  const size_t SZ_BHf = (size_t)BH * 4;              // 64 KiB

  // mode select: full-S clean (5 planes) > full-S aliased (4 planes) > chunked
  const size_t nsubF = S_LEN / CH2;  // 64
  const size_t fixedF = 2 * SZ_BHf + 4 * nsubF * SZ_BHf + SZ_WT;
  int Sc;
  int clean = 0;
  if (fixedF + 5 * SZ_HB <= ws_size) { Sc = S_LEN; clean = 1; }
  else if (fixedF + 4 * SZ_HB <= ws_size) { Sc = S_LEN; }
  else {
    Sc = 32;
    const int cands[6] = {1024, 512, 256, 128, 64, 32};
    for (int i = 0; i < 6; i++) {
      int c = cands[i];
      size_t nsub = (size_t)c / CH2;
      size_t need = 2 * SZ_BHf + 4 * nsub * SZ_BHf + SZ_WT + 2 * SZ_HB + 3ull * c * BH * 2;
      if (need <= ws_size) { Sc = c; break; }
    }
  }
  const int full = (Sc == S_LEN);
  const int nsub = Sc / CH2;
  const int nouter = S_LEN / Sc;

  char* p = (char*)d_ws;
  float* cstate = (float*)p; p += SZ_BHf;
  float* pooled = (float*)p; p += SZ_BHf;
  float* pmax   = (float*)p; p += (size_t)nsub * SZ_BHf;
  float* Ac     = (float*)p; p += (size_t)nsub * SZ_BHf;
  float* Bc     = (float*)p; p += (size_t)nsub * SZ_BHf;
  float* carry  = (float*)p; p += (size_t)nsub * SZ_BHf;
  ushort_t* Wt  = (ushort_t*)p; p += SZ_WT;
  // planes
  ushort_t* E  = (ushort_t*)p; p += SZ_HB;      // embedding / L0 highway
  ushort_t *X0, *F0, *R0, *O0 = nullptr, *OB = nullptr;
  if (full) {
    X0 = (ushort_t*)p; p += SZ_HB;
    F0 = (ushort_t*)p; p += SZ_HB;
    R0 = (ushort_t*)p; p += SZ_HB;
    O0 = clean ? ((ushort_t*)p) : E;  // clean: 5th plane; else alias highway (UB-free)
  } else {
    OB = (ushort_t*)p; p += SZ_HB;    // chunked: separate full-S output plane
    X0 = (ushort_t*)p; p += (size_t)Sc * BH * 2;
    F0 = (ushort_t*)p; p += (size_t)Sc * BH * 2;
    R0 = (ushort_t*)p;
  }

  gather_kernel<<<2048, 256, 0, stream>>>(x, (const float4*)embed, (uint4*)E);
  wt_kernel<<<1536, 256, 0, stream>>>(W, Wt);

  const int p1_blocks = (nsub * (BH / 4)) / 256;
  const int gemm_blocks = ((Sc * B_SZ) / 128) * (N_COLS / 128);
  for (int l = 0; l < 2; l++) {
    const ushort_t* Wtl = Wt + (size_t)l * N_COLS * D_DIM;
    const float* bl = b + (size_t)l * 2 * H_DIM;
    for (int ci = 0; ci < nouter; ci++) {
      const size_t off = (size_t)ci * Sc * BH;
      const ushort_t* Ain = full ? (l == 0 ? E : O0) : ((l == 0 ? E : OB) + off);
      sru_gemm_bf16<<<gemm_blocks, 256, 0, stream>>>(Ain, Wtl, X0, F0, R0);
      scan_pass1<<<p1_blocks, 256, 0, stream>>>(F0, X0, bl, Ac, Bc);
      scan_carry<<<BH / 256, 256, 0, stream>>>(Ac, Bc, carry, cstate, nsub, ci == 0);
      if (l == 0) {
        const ushort_t* hwp = full ? E : E + off;
        ushort_t* obp = full ? O0 : OB + off;
        scan_pass2<0><<<p1_blocks, 256, 0, stream>>>(F0, X0, R0, hwp, obp, bl, carry,
                                                     pmax, ci == 0);
      } else {
        const ushort_t* hwp = full ? O0 : OB + off;
        scan_pass2<1><<<p1_blocks, 256, 0, stream>>>(F0, X0, R0, hwp, nullptr, bl, carry,
                                                     pmax, ci == 0);
      }
    }
  }

  pool_kernel<<<BH / 256, 256, 0, stream>>>(pmax, pooled, nsub);
  out_gemm<<<B_SZ, 256, 0, stream>>>(pooled, Wc, bc, out);
}

// Round 9
// 645.655 us; speedup vs baseline: 1.2679x; 1.1867x over previous
//
#include <hip/hip_runtime.h>
#include <cmath>

// Problem constants (from reference)
#define S_LEN 2048
#define B_SZ 32
#define D_DIM 512
#define H_DIM 512
#define C_NUM 10
#define M_ROWS (S_LEN * B_SZ)   // 65536
#define BH (B_SZ * H_DIM)       // 16384 (= 2^14)
#define N_COLS (3 * H_DIM)      // 1536
#define CH2 32                  // subchunk length for the parallel scan

typedef __bf16 bf16_t;
typedef bf16_t bf16x8 __attribute__((ext_vector_type(8)));
typedef float f32x4 __attribute__((ext_vector_type(4)));
typedef unsigned short ushort_t;

// Tiled plane layout (512-col planes): elem(m,k) at
//   (m>>7)*65536 + (k>>3)*1024 + (m&127)*8 + (k&7)
// == the GEMM LDS image, so global->LDS staging is a linear copy.
__device__ __forceinline__ size_t tadr(int m, int k) {
  return ((size_t)(m >> 7) << 16) + ((size_t)(k >> 3) << 10) +
         ((size_t)(m & 127) << 3) + (size_t)(k & 7);
}

__device__ __forceinline__ unsigned int f2bf(float f) {
  union { float f; unsigned int u; } a;
  a.f = f;
  unsigned int r = a.u + 0x7FFFu + ((a.u >> 16) & 1u);  // RNE
  return r >> 16;
}
__device__ __forceinline__ unsigned int pack2bf(float lo, float hi) {
  return f2bf(lo) | (f2bf(hi) << 16);
}
__device__ __forceinline__ float bflo(unsigned int u) {
  union { unsigned int u; float f; } a; a.u = u << 16; return a.f;
}
__device__ __forceinline__ float bfhi(unsigned int u) {
  union { unsigned int u; float f; } a; a.u = u & 0xffff0000u; return a.f;
}
__device__ __forceinline__ float sigf(float x) {
  return 1.f / (1.f + __expf(-x));
}
__device__ __forceinline__ float tanh_fast(float c) {
  float e = __expf(2.f * c);
  return 1.f - 2.f / (e + 1.f);
}
__device__ __forceinline__ void load16_lds(const void* g, void* l) {
  __builtin_amdgcn_global_load_lds(
      (const __attribute__((address_space(1))) unsigned int*)g,
      (__attribute__((address_space(3))) unsigned int*)l, 16, 0, 0);
}

// ---------------- gather: E (tiled) = bf16(embed[x]) ----------------
// i indexes 16B chunks in (tile, row, kc) order: wave = one m-row (64 kc chunks),
// embed row read fully coalesced (2KB), x[m] wave-uniform.
__global__ void gather_kernel(const int* __restrict__ x,
                              const float* __restrict__ embed,
                              uint4* __restrict__ E4) {
  int i = blockIdx.x * blockDim.x + threadIdx.x;
  const int total = M_ROWS * 64;
  int stride = gridDim.x * blockDim.x;
  for (; i < total; i += stride) {
    int tile = i >> 13;
    int rem = i & 8191;
    int row = rem >> 6;
    int kc = rem & 63;
    int m = tile * 128 + row;
    const float4* src = (const float4*)(embed + (size_t)x[m] * 512 + kc * 8);
    float4 a = src[0], bq = src[1];
    // dest chunk index = tile*8192 + kc*128 + row
    E4[(size_t)tile * 8192 + kc * 128 + row] =
        make_uint4(pack2bf(a.x, a.y), pack2bf(a.z, a.w),
                   pack2bf(bq.x, bq.y), pack2bf(bq.z, bq.w));
  }
}

// ---------------- W -> Wt (tiled, transposed, bf16) ----------------
// Wt l-plane = 12 n-tiles x 65536; write-side fully linear.
__global__ __launch_bounds__(256) void wt_kernel(const float* __restrict__ W,
                                                 ushort_t* __restrict__ Wt) {
  int e = blockIdx.x * blockDim.x + threadIdx.x;  // 2 * 786432
  if (e >= 2 * 786432) return;
  int l = e / 786432;
  int t = e - l * 786432;
  int ntile = t >> 16;
  int rr = t & 65535;
  int kc = rr >> 10;
  int row = (rr >> 3) & 127;
  int kk = t & 7;
  int n = ntile * 128 + row;
  int k = kc * 8 + kk;
  Wt[e] = (ushort_t)f2bf(W[(size_t)l * D_DIM * N_COLS + (size_t)k * N_COLS + n]);
}

// ---------------- bf16 MFMA GEMM over tiled planes ----------------
// Tile 128x128, BK=32, double-buffered. Staging = linear 8KB copies (coalesced).
// mfma(bfr, af): D col(lane&15)<->m, row<->n. Epilogue stores tiled gate planes:
// lanes interleave into two dense 256B chunks per store instr.
__global__ __launch_bounds__(256, 3) void sru_gemm_bf16(
    const ushort_t* __restrict__ At,  // tiled A plane (absolute tiles)
    int tile0,                        // starting m-tile of this chunk
    const ushort_t* __restrict__ Bt,  // tiled W plane (12 n-tiles)
    ushort_t* __restrict__ xt_out, ushort_t* __restrict__ f_out,
    ushort_t* __restrict__ r_out) {
  __shared__ ushort_t As[2][4096];  // 8KB per buf = [kc 0..3][row 0..127][8]
  __shared__ ushort_t Bs[2][4096];
  const int t = threadIdx.x;
  const int wave = t >> 6, lane = t & 63;
  // bijective XCD swizzle (gridDim.x % 8 == 0 for all our grids)
  const int cpx = gridDim.x >> 3;
  const int swz = (blockIdx.x & 7) * cpx + (blockIdx.x >> 3);
  const int nb = swz % 12, mb = swz / 12;
  const int m0 = mb * 128, n0 = nb * 128;
  const int wm = wave & 1, wn = wave >> 1;
  const int lrow = lane >> 4, lcol = lane & 15;

  f32x4 acc[4][4];
#pragma unroll
  for (int i = 0; i < 4; i++)
#pragma unroll
    for (int j = 0; j < 4; j++) acc[i][j] = (f32x4){0.f, 0.f, 0.f, 0.f};

  const ushort_t* Ab = At + ((size_t)(tile0 + mb) << 16);
  const ushort_t* Bb = Bt + ((size_t)nb << 16);
  const int c0 = wave * 2;          // each wave stages 2x512-elem chunks per matrix
  const int le = lane * 8;          // lane element offset (16B per lane)

#define STAGE(buf, k0)                                                      \
  do {                                                                      \
    load16_lds(Ab + (k0) * 128 + (c0 + 0) * 512 + le, &As[buf][(c0 + 0) * 512]); \
    load16_lds(Ab + (k0) * 128 + (c0 + 1) * 512 + le, &As[buf][(c0 + 1) * 512]); \
    load16_lds(Bb + (k0) * 128 + (c0 + 0) * 512 + le, &Bs[buf][(c0 + 0) * 512]); \
    load16_lds(Bb + (k0) * 128 + (c0 + 1) * 512 + le, &Bs[buf][(c0 + 1) * 512]); \
  } while (0)

  STAGE(0, 0);
  __syncthreads();
  int cur = 0;
  for (int step = 0; step < 16; ++step) {
    if (step + 1 < 16) STAGE(cur ^ 1, (step + 1) * 32);
    bf16x8 af[4], bfr[4];
#pragma unroll
    for (int mi = 0; mi < 4; mi++)
      af[mi] = *reinterpret_cast<const bf16x8*>(
          &As[cur][(lrow * 128 + wm * 64 + mi * 16 + lcol) * 8]);
#pragma unroll
    for (int ni = 0; ni < 4; ni++)
      bfr[ni] = *reinterpret_cast<const bf16x8*>(
          &Bs[cur][(lrow * 128 + wn * 64 + ni * 16 + lcol) * 8]);
#pragma unroll
    for (int mi = 0; mi < 4; mi++)
#pragma unroll
      for (int ni = 0; ni < 4; ni++)
        acc[mi][ni] = __builtin_amdgcn_mfma_f32_16x16x32_bf16(
            bfr[ni], af[mi], acc[mi][ni], 0, 0, 0);
    __syncthreads();
    cur ^= 1;
  }
#undef STAGE

  // epilogue: tiled stores (local m), 8B packed, dense per wave-instruction
  const int region = n0 >> 9;  // 0=xt, 1=f, 2=r
  ushort_t* outp = region == 0 ? xt_out : (region == 1 ? f_out : r_out);
  const int nloc0 = (n0 & 511) + wn * 64 + lrow * 4;
#pragma unroll
  for (int mi = 0; mi < 4; mi++) {
    const int m = m0 + wm * 64 + mi * 16 + lcol;
    const size_t mpart = ((size_t)(m >> 7) << 16) + ((size_t)(m & 127) << 3);
#pragma unroll
    for (int ni = 0; ni < 4; ni++) {
      const int nloc = nloc0 + ni * 16;
      size_t ad = mpart + ((size_t)(nloc >> 3) << 10) + (nloc & 7);
      uint2 pk;
      pk.x = pack2bf(acc[mi][ni][0], acc[mi][ni][1]);
      pk.y = pack2bf(acc[mi][ni][2], acc[mi][ni][3]);
      *(uint2*)&outp[ad] = pk;
    }
  }
}

// ---------------- chunk-parallel scan over tiled planes ----------------
// Thread = (ch, hc, b): 8 h-lanes (one 16B tiled chunk) per load, walks s.
// Gates use LOCAL m; sigmoid(+bias) applied on the fly.
__global__ void scan_pass1(const ushort_t* __restrict__ f, const ushort_t* __restrict__ xt,
                           const float* __restrict__ bl,
                           float* __restrict__ Ac, float* __restrict__ Bc) {
  int gid = blockIdx.x * blockDim.x + threadIdx.x;  // nsub * 2048
  int ch = gid >> 11;
  int rem = gid & 2047;
  int hc = rem >> 5, b = rem & 31;
  int h0 = hc << 3;
  float bf_[8];
#pragma unroll
  for (int j = 0; j < 8; j++) bf_[j] = bl[h0 + j];
  float Aa[8], Bv[8];
#pragma unroll
  for (int j = 0; j < 8; j++) { Aa[j] = 1.f; Bv[j] = 0.f; }
  const int mbase = ch << 10;
  for (int s = 0; s < CH2; s++) {
    int m = mbase + (s << 5) + b;
    size_t ga = ((size_t)(m >> 7) << 16) + ((size_t)hc << 10) + ((m & 127) << 3);
    uint4 fq = *(const uint4*)&f[ga];
    uint4 xq = *(const uint4*)&xt[ga];
    unsigned int fw[4] = {fq.x, fq.y, fq.z, fq.w};
    unsigned int xw[4] = {xq.x, xq.y, xq.z, xq.w};
#pragma unroll
    for (int w = 0; w < 4; w++) {
      float fa = sigf(bflo(fw[w]) + bf_[2 * w]);
      float fb = sigf(bfhi(fw[w]) + bf_[2 * w + 1]);
      Bv[2 * w]     = fa * Bv[2 * w]     + (1.f - fa) * bflo(xw[w]);
      Bv[2 * w + 1] = fb * Bv[2 * w + 1] + (1.f - fb) * bfhi(xw[w]);
      Aa[2 * w] *= fa;
      Aa[2 * w + 1] *= fb;
    }
  }
  int lin = ch * BH + b * 512 + h0;
#pragma unroll
  for (int j = 0; j < 8; j++) { Ac[lin + j] = Aa[j]; Bc[lin + j] = Bv[j]; }
}

__global__ void scan_carry(const float* __restrict__ Ac, const float* __restrict__ Bc,
                           float* __restrict__ carry, float* __restrict__ cstate,
                           int nsub, int first) {
  int rem = blockIdx.x * blockDim.x + threadIdx.x;  // BH
  float c = first ? 0.f : cstate[rem];
  for (int ch = 0; ch < nsub; ch++) {
    int idx = ch * BH + rem;
    carry[idx] = c;
    c = Ac[idx] * c + Bc[idx];
  }
  cstate[rem] = c;
}

// LAST=0: write highway out to ob (tiled, absolute m; may alias hw — both
// non-restrict, per-thread load-before-store on same 16B). LAST=1: only pmax.
template <int LAST>
__global__ void scan_pass2(const ushort_t* __restrict__ f, const ushort_t* __restrict__ xt,
                           const ushort_t* __restrict__ r, const ushort_t* hw,
                           ushort_t* ob, const float* __restrict__ bl,
                           const float* __restrict__ carry, float* __restrict__ pmax,
                           int first_outer, int m0abs) {
  int gid = blockIdx.x * blockDim.x + threadIdx.x;  // nsub * 2048
  int ch = gid >> 11;
  int rem = gid & 2047;
  int hc = rem >> 5, b = rem & 31;
  int h0 = hc << 3;
  float bf_[8], br_[8];
#pragma unroll
  for (int j = 0; j < 8; j++) { bf_[j] = bl[h0 + j]; br_[j] = bl[512 + h0 + j]; }
  int lin = ch * BH + b * 512 + h0;
  float c[8], pm[8];
#pragma unroll
  for (int j = 0; j < 8; j++) { c[j] = carry[lin + j]; pm[j] = -1e30f; }
  const int mbase = ch << 10;
  for (int s = 0; s < CH2; s++) {
    int ml = mbase + (s << 5) + b;
    size_t ga = ((size_t)(ml >> 7) << 16) + ((size_t)hc << 10) + ((ml & 127) << 3);
    int ma = m0abs + ml;
    size_t ha = ((size_t)(ma >> 7) << 16) + ((size_t)hc << 10) + ((ma & 127) << 3);
    uint4 fq = *(const uint4*)&f[ga];
    uint4 xq = *(const uint4*)&xt[ga];
    uint4 rq = *(const uint4*)&r[ga];
    uint4 hq = *(const uint4*)&hw[ha];
    unsigned int fw[4] = {fq.x, fq.y, fq.z, fq.w};
    unsigned int xw[4] = {xq.x, xq.y, xq.z, xq.w};
    unsigned int rw[4] = {rq.x, rq.y, rq.z, rq.w};
    unsigned int hv[4] = {hq.x, hq.y, hq.z, hq.w};
    unsigned int ow[4];
#pragma unroll
    for (int w = 0; w < 4; w++) {
      float fa = sigf(bflo(fw[w]) + bf_[2 * w]);
      float fb = sigf(bfhi(fw[w]) + bf_[2 * w + 1]);
      float ra = sigf(bflo(rw[w]) + br_[2 * w]);
      float rb = sigf(bfhi(rw[w]) + br_[2 * w + 1]);
      c[2 * w]     = fa * c[2 * w]     + (1.f - fa) * bflo(xw[w]);
      c[2 * w + 1] = fb * c[2 * w + 1] + (1.f - fb) * bfhi(xw[w]);
      float oa = ra * tanh_fast(c[2 * w]) + (1.f - ra) * bflo(hv[w]);
      float obv = rb * tanh_fast(c[2 * w + 1]) + (1.f - rb) * bfhi(hv[w]);
      if (LAST) {
        pm[2 * w] = fmaxf(pm[2 * w], oa);
        pm[2 * w + 1] = fmaxf(pm[2 * w + 1], obv);
      } else {
        ow[w] = pack2bf(oa, obv);
      }
    }
    if (!LAST) *(uint4*)&ob[ha] = make_uint4(ow[0], ow[1], ow[2], ow[3]);
  }
  if (LAST) {
    if (first_outer) {
#pragma unroll
      for (int j = 0; j < 8; j++) pmax[lin + j] = pm[j];
    } else {
#pragma unroll
      for (int j = 0; j < 8; j++) pmax[lin + j] = fmaxf(pmax[lin + j], pm[j]);
    }
  }
}

// ---------------- pool: max over subchunk slots, double tanh ----------------
__global__ void pool_kernel(const float* __restrict__ pmax, float* __restrict__ pooled,
                            int nsub) {
  int rem = blockIdx.x * blockDim.x + threadIdx.x;  // BH
  float m = -1e30f;
  for (int ch = 0; ch < nsub; ch++) m = fmaxf(m, pmax[ch * BH + rem]);
  pooled[rem] = tanhf(tanhf(m));  // max(tanh(h)) == tanh(max(h)) (monotone)
}

// ---------------- final projection (tiny) ----------------
__global__ void out_gemm(const float* __restrict__ pooled, const float* __restrict__ Wc,
                         const float* __restrict__ bc, float* __restrict__ out) {
  __shared__ float pt[H_DIM];
  int b = blockIdx.x;
  for (int i = threadIdx.x; i < H_DIM; i += blockDim.x) pt[i] = pooled[b * H_DIM + i];
  __syncthreads();
  if (threadIdx.x < C_NUM) {
    int c = threadIdx.x;
    float acc = bc[c];
    for (int hh = 0; hh < H_DIM; hh++) acc = fmaf(pt[hh], Wc[hh * C_NUM + c], acc);
    out[b * C_NUM + c] = acc;
  }
}

extern "C" void kernel_launch(void* const* d_in, const int* in_sizes, int n_in,
                              void* d_out, int out_size, void* d_ws, size_t ws_size,
                              hipStream_t stream) {
  const int* x = (const int*)d_in[0];
  const float* embed = (const float*)d_in[1];
  const float* W = (const float*)d_in[2];
  const float* b = (const float*)d_in[3];
  const float* Wc = (const float*)d_in[4];
  const float* bc = (const float*)d_in[5];
  float* out = (float*)d_out;

  const size_t SZ_HB = (size_t)M_ROWS * H_DIM * 2;   // 64 MiB (bf16 full-S plane)
  const size_t SZ_WT = 2ull * N_COLS * D_DIM * 2;    // 3 MiB
  const size_t SZ_BHf = (size_t)BH * 4;              // 64 KiB

  // mode select: full-S clean (5 planes) > full-S aliased (4 planes) > chunked
  const size_t nsubF = S_LEN / CH2;  // 64
  const size_t fixedF = 2 * SZ_BHf + 4 * nsubF * SZ_BHf + SZ_WT;
  int Sc;
  int clean = 0;
  if (fixedF + 5 * SZ_HB <= ws_size) { Sc = S_LEN; clean = 1; }
  else if (fixedF + 4 * SZ_HB <= ws_size) { Sc = S_LEN; }
  else {
    Sc = 32;
    const int cands[6] = {1024, 512, 256, 128, 64, 32};
    for (int i = 0; i < 6; i++) {
      int c = cands[i];
      size_t nsub = (size_t)c / CH2;
      size_t need = 2 * SZ_BHf + 4 * nsub * SZ_BHf + SZ_WT + 2 * SZ_HB + 3ull * c * BH * 2;
      if (need <= ws_size) { Sc = c; break; }
    }
  }
  const int full = (Sc == S_LEN);
  const int nsub = Sc / CH2;
  const int nouter = S_LEN / Sc;

  char* p = (char*)d_ws;
  float* cstate = (float*)p; p += SZ_BHf;
  float* pooled = (float*)p; p += SZ_BHf;
  float* pmax   = (float*)p; p += (size_t)nsub * SZ_BHf;
  float* Ac     = (float*)p; p += (size_t)nsub * SZ_BHf;
  float* Bc     = (float*)p; p += (size_t)nsub * SZ_BHf;
  float* carry  = (float*)p; p += (size_t)nsub * SZ_BHf;
  ushort_t* Wt  = (ushort_t*)p; p += SZ_WT;
  // planes (all tiled layout)
  ushort_t* E  = (ushort_t*)p; p += SZ_HB;      // embedding / L0 highway
  ushort_t *X0, *F0, *R0, *O0 = nullptr, *OB = nullptr;
  if (full) {
    X0 = (ushort_t*)p; p += SZ_HB;
    F0 = (ushort_t*)p; p += SZ_HB;
    R0 = (ushort_t*)p; p += SZ_HB;
    O0 = clean ? ((ushort_t*)p) : E;  // clean: 5th plane; else alias highway (UB-free)
  } else {
    OB = (ushort_t*)p; p += SZ_HB;    // chunked: separate full-S output plane
    X0 = (ushort_t*)p; p += (size_t)Sc * BH * 2;
    F0 = (ushort_t*)p; p += (size_t)Sc * BH * 2;
    R0 = (ushort_t*)p;
  }

  gather_kernel<<<2048, 256, 0, stream>>>(x, embed, (uint4*)E);
  wt_kernel<<<6144, 256, 0, stream>>>(W, Wt);

  const int p1_blocks = (nsub * 2048) / 256;
  const int gemm_blocks = ((Sc * B_SZ) / 128) * (N_COLS / 128);
  for (int l = 0; l < 2; l++) {
    const ushort_t* Wtl = Wt + (size_t)l * N_COLS * D_DIM;
    const float* bl = b + (size_t)l * 2 * H_DIM;
    for (int ci = 0; ci < nouter; ci++) {
      const int m0abs = ci * Sc * B_SZ;        // absolute starting row of chunk
      const int tile0 = m0abs >> 7;            // absolute starting m-tile
      const ushort_t* Ain = full ? (l == 0 ? E : O0) : (l == 0 ? E : OB);
      sru_gemm_bf16<<<gemm_blocks, 256, 0, stream>>>(Ain, tile0, Wtl, X0, F0, R0);
      scan_pass1<<<p1_blocks, 256, 0, stream>>>(F0, X0, bl, Ac, Bc);
      scan_carry<<<BH / 256, 256, 0, stream>>>(Ac, Bc, carry, cstate, nsub, ci == 0);
      if (l == 0) {
        scan_pass2<0><<<p1_blocks, 256, 0, stream>>>(F0, X0, R0, E, full ? O0 : OB,
                                                     bl, carry, pmax, ci == 0, m0abs);
      } else {
        const ushort_t* hwp = full ? O0 : OB;
        scan_pass2<1><<<p1_blocks, 256, 0, stream>>>(F0, X0, R0, hwp, nullptr,
                                                     bl, carry, pmax, ci == 0, m0abs);
      }
    }
  }

  pool_kernel<<<BH / 256, 256, 0, stream>>>(pmax, pooled, nsub);
  out_gemm<<<B_SZ, 256, 0, stream>>>(pooled, Wc, bc, out);
}